// Round 13
// baseline (6591.428 us; speedup 1.0000x reference)
//
#include <hip/hip_runtime.h>

typedef _Float16 f16;
typedef _Float16 f16x2 __attribute__((ext_vector_type(2)));
typedef _Float16 f16x8 __attribute__((ext_vector_type(8)));
typedef float    f32x4 __attribute__((ext_vector_type(4)));

// ---------------- static device scratch --------------------------------------
__device__ f16   g_Xpad [64u*1028u*512u];   // conv1 input (B,T+4,512): ch0-255 coarse, 256-511 f3
__device__ f16   g_fseqA[64u*1024u*256u];   // h stream: f0
__device__ f16   g_fseqB[64u*1024u*256u];   // h stream: f1
__device__ f16   g_fseqC[64u*1024u*256u];   // h stream: f2
__device__ float g_xg32 [3u*64u*1048576u];  // xg streams f1..f3: [l][b][t][1024] fp32, permuted rows
__device__ f16   g_c2in [64u*1026u*256u];   // conv2 input (B,T+2,256), padded
__device__ f16   g_c3in [64u*1024u*128u];   // conv3 input (B,T,128)
// whh/wih octet-major: [L][ko:32][r:1024][kl:8]; k=ko*8+kl, r=u*4+q (orig row g=q*256+u)
__device__ f16   g_whhT2[5u*262144u];
__device__ f16   g_wihO [3u*262144u];
__device__ float g_biasP[3*1024];           // permuted bih+bhh for f1..f3
__device__ f16   g_B1   [256u*2560u];       // conv1 weight as GEMM B [oc][r*512+ic]
__device__ f16   g_B2   [128u*768u];        // conv2 weight as GEMM B [oc][r*256+ic]
__device__ float g_xg0  [2*64*1024];        // static xg for coarse/f0, permuted rows
__device__ float g_cat512[64*512];
__device__ float g_h    [64*256];
__device__ float g_feats[64*512];
__device__ float g_osc  [64*1024];
__device__ float g_smean[1024];
__device__ float g_cpar [64*4];
__device__ float g_enh  [64*1024];
// progress flags, one per 8 steps, value = group+1. Zeroed every launch (k_zero).
__device__ unsigned g_hflag[3*64*128];      // h streams (f0,f1,f2)
__device__ unsigned g_pflag[3*64*128];      // xg streams (P1,P2,P3)

// ---------------- helpers ----------------------------------------------------
__device__ inline float fdot2f(f16x2 a, f16x2 b, float c) {
#if __has_builtin(__builtin_amdgcn_fdot2)
  return __builtin_amdgcn_fdot2(a, b, c, false);
#else
  return c + (float)a[0]*(float)b[0] + (float)a[1]*(float)b[1];
#endif
}
__device__ inline float sigm_fast(float x) { return 1.0f / (1.0f + __expf(-x)); }
__device__ inline float tanh_fast(float x) { float e = __expf(2.0f*x); return 1.0f - 2.0f/(e + 1.0f); }
__device__ inline float lrelu(float x) { return x < 0.0f ? 0.2f*x : x; }
__device__ __forceinline__ void dot8x(f16x8 w, f16x8 h, float& a) {
  a = fdot2f(__builtin_shufflevector(w, w, 0, 1), __builtin_shufflevector(h, h, 0, 1), a);
  a = fdot2f(__builtin_shufflevector(w, w, 2, 3), __builtin_shufflevector(h, h, 2, 3), a);
  a = fdot2f(__builtin_shufflevector(w, w, 4, 5), __builtin_shufflevector(h, h, 4, 5), a);
  a = fdot2f(__builtin_shufflevector(w, w, 6, 7), __builtin_shufflevector(h, h, 6, 7), a);
}
// RELAXED spin + one ACQUIRE, single poller (tau==0), broadcast via barrier.
__device__ __forceinline__ void wait_ge(const unsigned* p, unsigned want) {
  while (__hip_atomic_load(p, __ATOMIC_RELAXED, __HIP_MEMORY_SCOPE_AGENT) < want) {}
  unsigned v;
  do { v = __hip_atomic_load(p, __ATOMIC_ACQUIRE, __HIP_MEMORY_SCOPE_AGENT); } while (v < want);
}

// ---------------- weight prep (unchanged blob layout) -------------------------
__global__ void __launch_bounds__(256) k_prep_whh(const float* cw, const float* f0w, const float* fw) {
  int bid = blockIdx.x;               // 5120 = L*1024 + g
  int L = bid >> 10, g = bid & 1023, k = threadIdx.x;
  const float* src = (L == 0) ? cw : (L == 1) ? f0w : (fw + (size_t)(L-2)*262144u);
  int q = g >> 8, u = g & 255, r = u*4 + q;
  int ko = k >> 3, kl = k & 7;
  g_whhT2[(size_t)L*262144u + (size_t)(ko*1024 + r)*8u + kl] = (f16)src[(size_t)g*256 + k];
}
__global__ void __launch_bounds__(256) k_prep_wih(const float* fwih, const float* fbih, const float* fbhh) {
  int bid = blockIdx.x;               // 3072 = L*1024 + g
  int L = bid >> 10, g = bid & 1023, k = threadIdx.x;
  int q = g >> 8, u = g & 255, r = u*4 + q;
  int ko = k >> 3, kl = k & 7;
  g_wihO[(size_t)L*262144u + (size_t)(ko*1024 + r)*8u + kl] = (f16)fwih[(size_t)L*262144u + (size_t)g*256u + k];
  if (k == 0) g_biasP[L*1024 + r] = fbih[L*1024 + g] + fbhh[L*1024 + g];
}
__global__ void __launch_bounds__(256) k_prep_c1(const float* w) {
  int idx = blockIdx.x*256 + threadIdx.x;        // 655360
  int oc = idx / 2560, rem = idx % 2560, r = rem / 512, ic = rem % 512;
  g_B1[idx] = (f16)w[(size_t)oc*2560 + (size_t)ic*5 + r];
}
__global__ void __launch_bounds__(256) k_prep_c2(const float* w) {
  int idx = blockIdx.x*256 + threadIdx.x;        // 98304
  int oc = idx / 768, rem = idx % 768, r = rem / 256, ic = rem % 256;
  g_B2[idx] = (f16)w[(size_t)oc*768 + (size_t)ic*3 + r];
}
__global__ void __launch_bounds__(256) k_zero() {
  int idx = blockIdx.x*256 + threadIdx.x;        // 212992 = 832*256
  if (idx < 131072) {   // Xpad pad rows 0,1,1026,1027
    int b = idx >> 11, rem = idx & 2047, rr = rem >> 9, c = rem & 511;
    int row = (rr < 2) ? rr : 1024 + rr;
    g_Xpad[(size_t)b*526336u + (size_t)row*512u + c] = (f16)0.0f;
  } else if (idx < 163840) {   // c2in pad rows 0, 1025
    int i2 = idx - 131072;
    int b = i2 >> 9, rem = i2 & 511, rr = rem >> 8, c = rem & 255;
    int row = rr ? 1025 : 0;
    g_c2in[(size_t)b*262656u + (size_t)row*256u + c] = (f16)0.0f;
  } else {              // flags: MUST reset each launch (replay/graph safe)
    int i3 = idx - 163840;
    if (i3 < 24576) g_hflag[i3] = 0u;
    else            g_pflag[i3 - 24576] = 0u;
  }
}

// ---------------- small front-end ops ----------------------------------------
__global__ void __launch_bounds__(256) k_setup1(const float* z, const int* labels, const float* emb,
                                                const float* npw, const float* npb,
                                                const float* lg, const float* lb) {
  __shared__ float x[384];
  __shared__ float s1[256], s2[256];
  int b = blockIdx.x, tid = threadIdx.x;
  int lab = labels[b];
  for (int i = tid; i < 384; i += 256)
    x[i] = (i < 128) ? z[b*128 + i] : emb[lab*256 + (i - 128)];
  __syncthreads();
  float acc = npb[tid];
  for (int k = 0; k < 384; ++k) acc += npw[tid*384 + k]*x[k];
  s1[tid] = acc; s2[tid] = acc*acc; __syncthreads();
  for (int s = 128; s > 0; s >>= 1) { if (tid < s) { s1[tid]+=s1[tid+s]; s2[tid]+=s2[tid+s]; } __syncthreads(); }
  float m = s1[0]*(1.0f/256.0f), var = s2[0]*(1.0f/256.0f) - m*m;
  float hv = (acc - m)*(1.0f/sqrtf(var + 1e-5f))*lg[tid] + lb[tid];
  hv = lrelu(hv);
  g_h[b*256 + tid] = hv;
  g_cat512[b*512 + tid] = hv;
  g_cat512[b*512 + 256 + tid] = x[128 + tid];
}
__global__ void __launch_bounds__(1024) k_xg0(const float* cwih, const float* cbih, const float* cbhh,
                                              const float* fwih, const float* fbih, const float* fbhh) {
  int bid = blockIdx.x;               // 128 = layer*64+b
  int layer = bid >> 6, b = bid & 63;
  int gp = threadIdx.x, j = gp >> 2, q = gp & 3, g = q*256 + j;
  __shared__ float cat[512];
  if (gp < 512) cat[gp] = g_cat512[b*512 + gp];
  __syncthreads();
  const float* w = layer ? fwih : cwih;
  float acc = layer ? (fbih[g] + fbhh[g]) : (cbih[g] + cbhh[g]);
  for (int k = 0; k < 512; ++k) acc += w[(size_t)g*512 + k]*cat[k];
  g_xg0[(layer*64 + b)*1024 + gp] = acc;
}
__global__ void __launch_bounds__(256) k_osc(const float* w1, const float* b1v, const float* lg,
                                             const float* lb, const float* w2, const float* b2v) {
  __shared__ float hb[256], av[256], s1[256], s2[256];
  int b = blockIdx.x, tid = threadIdx.x;
  hb[tid] = g_h[b*256 + tid];
  __syncthreads();
  float acc = b1v[tid];
  for (int k = 0; k < 256; ++k) acc += w1[tid*256 + k]*hb[k];
  s1[tid] = acc; s2[tid] = acc*acc; __syncthreads();
  for (int s = 128; s > 0; s >>= 1) { if (tid < s) { s1[tid]+=s1[tid+s]; s2[tid]+=s2[tid+s]; } __syncthreads(); }
  float m = s1[0]*(1.0f/256.0f), var = s2[0]*(1.0f/256.0f) - m*m;
  av[tid] = lrelu((acc - m)*(1.0f/sqrtf(var + 1e-5f))*lg[tid] + lb[tid]);
  __syncthreads();
  for (int tt = tid; tt < 1024; tt += 256) {
    float o = b2v[tt];
    for (int i = 0; i < 256; ++i) o += w2[(size_t)tt*256 + i]*av[i];
    g_osc[b*1024 + tt] = tanhf(o);
  }
}
__global__ void __launch_bounds__(256) k_sinmean(const float* sw, const float* sb) {
  int tt = blockIdx.x*256 + threadIdx.x;   // grid 4
  const float F[6] = {0.19f, 0.21f, 0.23f, 0.25f, 0.27f, 0.29f};
  float tl = tt*(1.0f/1023.0f);
  float sc[12];
  for (int j = 0; j < 6; ++j) {
    float p = (6.2831853071795864f * tl) * F[j] * 1024.0f;
    sc[j] = sinf(p); sc[6 + j] = cosf(p);
  }
  float a = 0.0f;
  for (int i = 0; i < 128; ++i) {
    float s = sb[i];
    for (int j = 0; j < 12; ++j) s += sw[i*12 + j]*sc[j];
    a += s;
  }
  g_smean[tt] = a*(1.0f/128.0f);
}

// ---------------- the whole LSTM stack as ONE flag-chained dispatch ----------
// R9-proven schedule: 512 blocks x 512 thr, 1 block/CU, two implicit dispatch
// waves (live chain depth <=4). Roles by bid>>6 (b = bid&63):
//  0 coarse | 1 f0 | 2 P1 | 3 f1 || 4 P2 | 5 f2 | 6 P3 | 7 f3
// Gate = ONE barrier/step: gates of unit u=tau>>2 live in lanes 4u..4u+3
// (permuted rows r=4u+q), so 6 quad shfl_xor gather i,f,g,o to lane q==0,
// which alone runs the update for units uA=tau>>2 and uB=128+uA (same 1280
// transcendental ops/block-step as R9 -- R11's regression was the 4x-redundant
// all-lane update, +700cy/step, confirmed by VALUBusy 58% & slower).
// gbuf deleted; double-buffered hbuf needs only the end-of-step barrier
// (iter t reads cur before the barrier; iter t+1 writes the other buffer).
// Dots + weight residency + P stage byte-identical to R9 (proven no-spill).
__global__ void __launch_bounds__(512, 2) k_chain() {
  int bid = blockIdx.x;             // 512
  int role = bid >> 6, b = bid & 63;
  int tau = threadIdx.x;            // 0..511
  bool isP = (role == 2) || (role == 4) || (role == 6);
  int lp = (role - 2) >> 1;                                      // P idx 0..2
  int Lg = (role==0)?0:(role==1)?1:(role==3)?2:(role==5)?3:4;    // gate whh layer

  __shared__ __align__(16) f16 wlds[65536];    // ko 0..7 (128 KB)
  __shared__ __align__(16) f16 hbuf[2][256];

  const f16* Wc = isP ? (g_wihO + (size_t)lp*262144u) : (g_whhT2 + (size_t)Lg*262144u);
#pragma unroll
  for (int i = 0; i < 16; ++i) {
    int o = i*512 + tau;
    *(f16x8*)(wlds + (size_t)o*8u) = *(const f16x8*)(Wc + (size_t)o*8u);
  }
  f16x8 wA[24], wB[24];                        // ko 8..31, rows tau / tau+512
  {
    const f16* wp = Wc + (size_t)(8*1024 + tau)*8u;
#pragma unroll
    for (int i = 0; i < 24; ++i) {
      wA[i] = *(const f16x8*)(wp + (size_t)i*8192u);
      wB[i] = *(const f16x8*)(wp + (size_t)i*8192u + 4096u);
    }
  }

  if (isP) {
    // -------- projection: xg_l(t) = wih_l . h_stream(t) + bias (R9 body) ------
    const f16* hs = ((lp==0) ? g_fseqA : (lp==1) ? g_fseqB : g_fseqC) + (size_t)b*262144u;
    const unsigned* hf = g_hflag + (lp*64 + b)*128;
    float* xo = g_xg32 + (size_t)(lp*64 + b)*1048576u;
    unsigned* pf = g_pflag + (lp*64 + b)*128;
    float bA = g_biasP[lp*1024 + tau], bB = g_biasP[lp*1024 + 512 + tau];
    __syncthreads();
#pragma unroll 1
    for (int t = 0; t < 1024; ++t) {
      if ((t & 7) == 0) {            // single poller + barrier broadcast
        if (tau == 0) wait_ge(hf + (t >> 3), (unsigned)(t >> 3) + 1u);
        __syncthreads();
      }
      if (tau < 32) *(f16x8*)(&hbuf[t & 1][tau*8]) = *(const f16x8*)(hs + (size_t)t*256u + tau*8);
      __syncthreads();
      const f16* hb = &hbuf[t & 1][0];
      float a0 = 0.f, a1 = 0.f, b0 = 0.f, b1 = 0.f;
#pragma unroll
      for (int ko = 0; ko < 8; ++ko) {
        f16x8 hv = *(const f16x8*)(hb + ko*8);
        f16x8 wa = *(const f16x8*)(wlds + (size_t)(ko*1024 + tau)*8u);
        f16x8 wb = *(const f16x8*)(wlds + (size_t)(ko*1024 + tau + 512)*8u);
        dot8x(wa, hv, a0); dot8x(wb, hv, b0);
      }
#pragma unroll
      for (int i = 0; i < 24; ++i) {
        f16x8 hv = *(const f16x8*)(hb + 64 + i*8);
        dot8x(wA[i], hv, a1); dot8x(wB[i], hv, b1);
      }
      xo[(size_t)t*1024u + tau]       = a0 + a1 + bA;
      xo[(size_t)t*1024u + 512 + tau] = b0 + b1 + bB;
      if ((t & 7) == 7) {
        __syncthreads();             // drains all waves' xg stores before flag
        if (tau == 0) __hip_atomic_store(pf + (t >> 3), (unsigned)(t >> 3) + 1u,
                                         __ATOMIC_RELEASE, __HIP_MEMORY_SCOPE_AGENT);
      }
    }
  } else {
    // -------- gate: recurrence, quad-gather to q==0, ONE barrier/step ---------
    bool dyn = (role >= 3);
    int lq = (role - 3) >> 1;       // xg stream idx (valid when dyn)
    int q = tau & 3, uA = tau >> 2, uB = 128 + uA;   // uA in [0,128)
    float cA = 0.0f, cB = 0.0f, sumA = 0.0f, sumB = 0.0f;
    f32x4 xsA = {0.f,0.f,0.f,0.f}, xsB = {0.f,0.f,0.f,0.f};
    const float* xp = nullptr;
    const unsigned* xf = nullptr;
    unsigned* hfo = nullptr;
    if (!dyn) {
      if (q == 0) {
        xsA = *(const f32x4*)(g_xg0 + (size_t)(Lg*64 + b)*1024u + 4*uA);
        xsB = *(const f32x4*)(g_xg0 + (size_t)(Lg*64 + b)*1024u + 512 + 4*uA);
      }
    } else {
      xp = g_xg32 + (size_t)(lq*64 + b)*1048576u;
      xf = g_pflag + (lq*64 + b)*128;
    }
    f16* obase; int ostride;
    if (role == 0)      { obase = g_Xpad  + (size_t)b*526336u + 1024;       ostride = 512; }
    else if (role == 1) { obase = g_fseqA + (size_t)b*262144u;              ostride = 256; }
    else if (role == 3) { obase = g_fseqB + (size_t)b*262144u;              ostride = 256; }
    else if (role == 5) { obase = g_fseqC + (size_t)b*262144u;              ostride = 256; }
    else                { obase = g_Xpad  + (size_t)b*526336u + 1024 + 256; ostride = 512; }
    int hop = (role == 1) ? 0 : (role == 3) ? 1 : (role == 5) ? 2 : -1;
    if (hop >= 0) hfo = g_hflag + (hop*64 + b)*128;
    if (tau < 256) hbuf[0][tau] = (f16)0.0f;
    __syncthreads();
    int cur = 0;
#pragma unroll 1
    for (int step = 0; step < 1024; ++step) {
      if (dyn && (step & 7) == 0) {  // single poller + barrier broadcast
        if (tau == 0) wait_ge(xf + (step >> 3), (unsigned)(step >> 3) + 1u);
        __syncthreads();
      }
      f32x4 xvA = xsA, xvB = xsB;
      if (dyn && q == 0) {           // issued before dots -> latency hidden
        xvA = *(const f32x4*)(xp + (size_t)step*1024u + 4*uA);
        xvB = *(const f32x4*)(xp + (size_t)step*1024u + 512 + 4*uA);
      }
      const f16* hb = &hbuf[cur][0];
      float a0 = 0.f, a1 = 0.f, b0 = 0.f, b1 = 0.f;
#pragma unroll
      for (int ko = 0; ko < 8; ++ko) {
        f16x8 hv = *(const f16x8*)(hb + ko*8);
        f16x8 wa = *(const f16x8*)(wlds + (size_t)(ko*1024 + tau)*8u);
        f16x8 wb = *(const f16x8*)(wlds + (size_t)(ko*1024 + tau + 512)*8u);
        dot8x(wa, hv, a0); dot8x(wb, hv, b0);
      }
#pragma unroll
      for (int i = 0; i < 24; ++i) {
        f16x8 hv = *(const f16x8*)(hb + 64 + i*8);
        dot8x(wA[i], hv, a1); dot8x(wB[i], hv, b1);
      }
      float va = a0 + a1;            // gate q of unit uA (row tau)
      float vb = b0 + b1;            // gate q of unit uB (row tau+512)
      // quad gather toward lane q==0: at q==0, va=i, g1=f, g2=g, g3=o
      float g1a = __shfl_xor(va, 1), g2a = __shfl_xor(va, 2), g3a = __shfl_xor(g1a, 2);
      float g1b = __shfl_xor(vb, 1), g2b = __shfl_xor(vb, 2), g3b = __shfl_xor(g1b, 2);
      int nxt = cur ^ 1;
      if (q == 0) {                  // 128 update lanes, 2 units each (R9 cost)
        float ii = sigm_fast(va  + xvA[0]), ff = sigm_fast(g1a + xvA[1]);
        float gg = tanh_fast(g2a + xvA[2]), oo = sigm_fast(g3a + xvA[3]);
        cA = ff*cA + ii*gg;
        float hA = oo*tanh_fast(cA); sumA += hA;
        hbuf[nxt][uA] = (f16)hA; obase[(size_t)step*ostride + uA] = (f16)hA;
        ii = sigm_fast(vb  + xvB[0]); ff = sigm_fast(g1b + xvB[1]);
        gg = tanh_fast(g2b + xvB[2]); oo = sigm_fast(g3b + xvB[3]);
        cB = ff*cB + ii*gg;
        float hB = oo*tanh_fast(cB); sumB += hB;
        hbuf[nxt][uB] = (f16)hB; obase[(size_t)step*ostride + uB] = (f16)hB;
      }
      __syncthreads();               // h writes visible; global stores drained
      if (hfo && (step & 7) == 7 && tau == 0)
        __hip_atomic_store(hfo + (step >> 3), (unsigned)(step >> 3) + 1u,
                           __ATOMIC_RELEASE, __HIP_MEMORY_SCOPE_AGENT);
      cur = nxt;
    }
    if (q == 0) {
      if (role == 0) {
        g_feats[b*512 + uA] = sumA*(1.0f/1024.0f);
        g_feats[b*512 + uB] = sumB*(1.0f/1024.0f);
      }
      if (role == 7) {
        g_feats[b*512 + 256 + uA] = sumA*(1.0f/1024.0f);
        g_feats[b*512 + 256 + uB] = sumB*(1.0f/1024.0f);
      }
    }
  }
}

// ---------------- fp16 MFMA GEMM (implicit conv1/conv2) ----------------------
__global__ void __launch_bounds__(256) k_gemm(int which,
                                              const float* cb, const float* bng, const float* bnb) {
  const f16* A; size_t a_bs; int a_rs, K; const f16* Bm;
  f16* outH; size_t o_bs; int o_rs;
  if (which == 2) {
    A = g_Xpad; a_bs = 526336u; a_rs = 512; K = 2560; Bm = g_B1;
    outH = g_c2in + 256; o_bs = 262656u; o_rs = 256;
  } else {
    A = g_c2in; a_bs = 262656u; a_rs = 256; K = 768; Bm = g_B2;
    outH = g_c3in; o_bs = 131072u; o_rs = 128;
  }
  int tid = threadIdx.x, wave = tid >> 6, lane = tid & 63;
  int m0 = blockIdx.x*128, n0 = blockIdx.y*64;
  __shared__ __align__(16) f16 Asm[128*72];
  __shared__ __align__(16) f16 Bsm[64*72];
  f32x4 acc[2][4];
#pragma unroll
  for (int i = 0; i < 2; ++i)
#pragma unroll
    for (int jj = 0; jj < 4; ++jj) { f32x4 zz = {0.f,0.f,0.f,0.f}; acc[i][jj] = zz; }
  int ar = tid & 127, ac = (tid >> 7)*32;
  int mrow = m0 + ar, abb = mrow >> 10, att = mrow & 1023;
  const f16* aptr = A + (size_t)abb*a_bs + (size_t)att*a_rs + ac;
  int br = tid & 63, bc = (tid >> 6)*16;
  const f16* bptr = Bm + (size_t)(n0 + br)*K + bc;
  int nkb = K >> 6;
  for (int kb = 0; kb < nkb; ++kb) {
    f16x8 av0 = *(const f16x8*)(aptr + 0);
    f16x8 av1 = *(const f16x8*)(aptr + 8);
    f16x8 av2 = *(const f16x8*)(aptr + 16);
    f16x8 av3 = *(const f16x8*)(aptr + 24);
    f16x8 bv0 = *(const f16x8*)(bptr + 0);
    f16x8 bv1 = *(const f16x8*)(bptr + 8);
    aptr += 64; bptr += 64;
    __syncthreads();
    *(f16x8*)(&Asm[ar*72 + ac + 0])  = av0;
    *(f16x8*)(&Asm[ar*72 + ac + 8])  = av1;
    *(f16x8*)(&Asm[ar*72 + ac + 16]) = av2;
    *(f16x8*)(&Asm[ar*72 + ac + 24]) = av3;
    *(f16x8*)(&Bsm[br*72 + bc + 0])  = bv0;
    *(f16x8*)(&Bsm[br*72 + bc + 8])  = bv1;
    __syncthreads();
#pragma unroll
    for (int ks = 0; ks < 2; ++ks) {
      int ko = ks*32 + (lane >> 4)*8;
      f16x8 a0 = *(const f16x8*)(&Asm[(wave*32 + (lane & 15))*72 + ko]);
      f16x8 a1 = *(const f16x8*)(&Asm[(wave*32 + 16 + (lane & 15))*72 + ko]);
#pragma unroll
      for (int nt = 0; nt < 4; ++nt) {
        f16x8 bf = *(const f16x8*)(&Bsm[(nt*16 + (lane & 15))*72 + ko]);
        acc[0][nt] = __builtin_amdgcn_mfma_f32_16x16x32_f16(a0, bf, acc[0][nt], 0, 0, 0);
        acc[1][nt] = __builtin_amdgcn_mfma_f32_16x16x32_f16(a1, bf, acc[1][nt], 0, 0, 0);
      }
    }
  }
  const float bnc = 0.99999500003749969f;  // 1/sqrt(1+1e-5)
#pragma unroll
  for (int mt = 0; mt < 2; ++mt)
#pragma unroll
    for (int nt = 0; nt < 4; ++nt)
#pragma unroll
      for (int r = 0; r < 4; ++r) {
        int m_loc = wave*32 + mt*16 + (lane >> 4)*4 + r;
        int n = n0 + nt*16 + (lane & 15);
        int mg = m0 + m_loc, ob = mg >> 10, ot = mg & 1023;
        float v = acc[mt][nt][r];
        v = (v + cb[n])*(bng[n]*bnc) + bnb[n];
        v = lrelu(v);
        outH[(size_t)ob*o_bs + (size_t)ot*o_rs + n] = (f16)v;
      }
}

// ---------------- cp head ----------------------------------------------------
__global__ void __launch_bounds__(128) k_cp(const float* w1, const float* b1v, const float* lg,
                                            const float* lb, const float* w2, const float* b2v) {
  __shared__ float ft[512], av[128], s1[128], s2[128];
  int b = blockIdx.x, tid = threadIdx.x;
  for (int i = tid; i < 512; i += 128) ft[i] = g_feats[b*512 + i];
  __syncthreads();
  float acc = b1v[tid];
  for (int k = 0; k < 512; ++k) acc += w1[tid*512 + k]*ft[k];
  s1[tid] = acc; s2[tid] = acc*acc; __syncthreads();
  for (int s = 64; s > 0; s >>= 1) { if (tid < s) { s1[tid]+=s1[tid+s]; s2[tid]+=s2[tid+s]; } __syncthreads(); }
  float m = s1[0]*(1.0f/128.0f), var = s2[0]*(1.0f/128.0f) - m*m;
  av[tid] = lrelu((acc - m)*(1.0f/sqrtf(var + 1e-5f))*lg[tid] + lb[tid]);
  __syncthreads();
  if (tid < 4) {
    float s = b2v[tid];
    for (int i = 0; i < 128; ++i) s += w2[tid*128 + i]*av[i];
    g_cpar[b*4 + tid] = 1.0f/(1.0f + expf(-s));
  }
}

// ---------------- conv3 + enhanced -------------------------------------------
__global__ void __launch_bounds__(256) k_enh(const float* w3, const float* b3) {
  int idx = blockIdx.x*256 + threadIdx.x;
  int b = idx >> 10, t = idx & 1023;
  const f16* xc = g_c3in + (size_t)idx*128u;
  bool hm = (t > 0), hp = (t < 1023);
  float pre = b3[0];
  for (int c = 0; c < 128; ++c) {
    float xm = hm ? (float)xc[c - 128] : 0.0f;
    float x0 = (float)xc[c];
    float xp = hp ? (float)xc[c + 128] : 0.0f;
    pre += xm*w3[c*3] + x0*w3[c*3 + 1] + xp*w3[c*3 + 2];
  }
  float base = tanhf(pre);
  float cp0 = g_cpar[b*4 + 0], cp1 = g_cpar[b*4 + 1], cp2 = g_cpar[b*4 + 2], cp3 = g_cpar[b*4 + 3];
  float freq  = 0.19f + 0.1f*cp0;
  float amp   = 1.0f + 2.0f*cp1;
  float phase = 6.2831853071795864f*cp2;
  float basel = -0.5f + cp3;
  float tl = t*(1.0f/1023.0f);
  float arg = ((6.2831853071795864f*freq)*1024.0f)*tl + phase;
  float card = amp*sinf(arg) + basel;
  g_enh[idx] = 0.1f*base + 0.1f*g_osc[idx] + 0.7f*card + 0.1f*g_smean[t];
}

__global__ void __launch_bounds__(256) k_out(const int* labels, const float* sw,
                                             const float* aw, const float* ab, float* out) {
  int idx = blockIdx.x*256 + threadIdx.x;
  int b = idx >> 10, t = idx & 1023;
  int lab = labels[b];
  float e = g_enh[idx], r;
  if (lab == 1) r = e;
  else if (lab == 2) r = sw[0]*e;
  else if (lab == 3) {
    float em = (t > 0)    ? g_enh[idx - 1] : 0.0f;
    float ep = (t < 1023) ? g_enh[idx + 1] : 0.0f;
    r = aw[0]*em + aw[1]*e + aw[2]*ep + ab[0];
  } else r = 0.0f;
  out[idx] = r;
}

// ---------------- launch ------------------------------------------------------
extern "C" void kernel_launch(void* const* d_in, const int* in_sizes, int n_in,
                              void* d_out, int out_size, void* d_ws, size_t ws_size,
                              hipStream_t stream) {
  const float* z       = (const float*)d_in[0];
  const int*   labels  = (const int*)  d_in[1];
  const float* emb     = (const float*)d_in[2];
  const float* np_w    = (const float*)d_in[3];
  const float* np_b    = (const float*)d_in[4];
  const float* np_ln_g = (const float*)d_in[5];
  const float* np_ln_b = (const float*)d_in[6];
  const float* c_wih   = (const float*)d_in[7];
  const float* c_whh   = (const float*)d_in[8];
  const float* c_bih   = (const float*)d_in[9];
  const float* c_bhh   = (const float*)d_in[10];
  const float* f0_wih  = (const float*)d_in[11];
  const float* f0_whh  = (const float*)d_in[12];
  const float* f0_bih  = (const float*)d_in[13];
  const float* f0_bhh  = (const float*)d_in[14];
  const float* f_wih   = (const float*)d_in[15];
  const float* f_whh   = (const float*)d_in[16];
  const float* f_bih   = (const float*)d_in[17];
  const float* f_bhh   = (const float*)d_in[18];
  const float* osc_w1  = (const float*)d_in[19];
  const float* osc_b1  = (const float*)d_in[20];
  const float* osc_ln_g= (const float*)d_in[21];
  const float* osc_ln_b= (const float*)d_in[22];
  const float* osc_w2  = (const float*)d_in[23];
  const float* osc_b2  = (const float*)d_in[24];
  const float* cp_w1   = (const float*)d_in[25];
  const float* cp_b1   = (const float*)d_in[26];
  const float* cp_ln_g = (const float*)d_in[27];
  const float* cp_ln_b = (const float*)d_in[28];
  const float* cp_w2   = (const float*)d_in[29];
  const float* cp_b2   = (const float*)d_in[30];
  const float* sin_w   = (const float*)d_in[31];
  const float* sin_b   = (const float*)d_in[32];
  const float* conv1_w = (const float*)d_in[33];
  const float* conv1_b = (const float*)d_in[34];
  const float* bn1_g   = (const float*)d_in[35];
  const float* bn1_b   = (const float*)d_in[36];
  const float* conv2_w = (const float*)d_in[37];
  const float* conv2_b = (const float*)d_in[38];
  const float* bn2_g   = (const float*)d_in[39];
  const float* bn2_b   = (const float*)d_in[40];
  const float* conv3_w = (const float*)d_in[41];
  const float* conv3_b = (const float*)d_in[42];
  const float* stress_w= (const float*)d_in[43];
  const float* amuse_w = (const float*)d_in[44];
  const float* amuse_b = (const float*)d_in[45];
  float* out = (float*)d_out;

  k_prep_whh<<<5120, 256, 0, stream>>>(c_whh, f0_whh, f_whh);
  k_prep_wih<<<3072, 256, 0, stream>>>(f_wih, f_bih, f_bhh);
  k_prep_c1 <<<2560, 256, 0, stream>>>(conv1_w);
  k_prep_c2 <<< 384, 256, 0, stream>>>(conv2_w);
  k_zero    <<< 832, 256, 0, stream>>>();
  k_setup1  <<<  64, 256, 0, stream>>>(z, labels, emb, np_w, np_b, np_ln_g, np_ln_b);
  k_xg0     <<< 128,1024, 0, stream>>>(c_wih, c_bih, c_bhh, f0_wih, f0_bih, f0_bhh);
  k_osc     <<<  64, 256, 0, stream>>>(osc_w1, osc_b1, osc_ln_g, osc_ln_b, osc_w2, osc_b2);
  k_sinmean <<<   4, 256, 0, stream>>>(sin_w, sin_b);

  k_chain   <<< 512, 512, 0, stream>>>();        // all 5 LSTM layers + 3 projections

  k_cp      <<<  64, 128, 0, stream>>>(cp_w1, cp_b1, cp_ln_g, cp_ln_b, cp_w2, cp_b2);
  k_gemm    <<<dim3(512, 4), 256, 0, stream>>>(2, conv1_b, bn1_g, bn1_b);   // conv1
  k_gemm    <<<dim3(512, 2), 256, 0, stream>>>(3, conv2_b, bn2_g, bn2_b);   // conv2
  k_enh     <<< 256, 256, 0, stream>>>(conv3_w, conv3_b);
  k_out     <<< 256, 256, 0, stream>>>(labels, stress_w, amuse_w, amuse_b, out);
}

// Round 14
// 4820.560 us; speedup vs baseline: 1.3674x; 1.3674x over previous
//
#include <hip/hip_runtime.h>

typedef _Float16 f16;
typedef _Float16 f16x2 __attribute__((ext_vector_type(2)));
typedef _Float16 f16x8 __attribute__((ext_vector_type(8)));
typedef float    f32x4 __attribute__((ext_vector_type(4)));

// ---------------- static device scratch --------------------------------------
__device__ f16   g_Xpad [64u*1028u*512u];   // conv1 input (B,T+4,512): ch0-255 coarse, 256-511 f3
__device__ f16   g_fseqA[64u*1024u*256u];   // h stream: f0
__device__ f16   g_fseqB[64u*1024u*256u];   // h stream: f1
__device__ f16   g_fseqC[64u*1024u*256u];   // h stream: f2
__device__ float g_xg32 [3u*64u*1048576u];  // xg streams f1..f3: [l][b][t][1024] fp32, permuted rows
__device__ f16   g_c2in [64u*1026u*256u];   // conv2 input (B,T+2,256), padded
__device__ f16   g_c3in [64u*1024u*128u];   // conv3 input (B,T,128)
// whh/wih octet-major: [L][ko:32][r:1024][kl:8]; k=ko*8+kl, r=u*4+q (orig row g=q*256+u)
__device__ f16   g_whhT2[5u*262144u];
__device__ f16   g_wihO [3u*262144u];
__device__ float g_biasP[3*1024];           // permuted bih+bhh for f1..f3
__device__ f16   g_B1   [256u*2560u];       // conv1 weight as GEMM B [oc][r*512+ic]
__device__ f16   g_B2   [128u*768u];        // conv2 weight as GEMM B [oc][r*256+ic]
__device__ float g_xg0  [2*64*1024];        // static xg for coarse/f0, permuted rows
__device__ float g_cat512[64*512];
__device__ float g_h    [64*256];
__device__ float g_feats[64*512];
__device__ float g_osc  [64*1024];
__device__ float g_smean[1024];
__device__ float g_cpar [64*4];
__device__ float g_enh  [64*1024];
// progress flags, one per 8 steps, value = group+1. Zeroed every launch (k_zero).
__device__ unsigned g_hflag[3*64*128];      // h streams (f0,f1,f2)
__device__ unsigned g_pflag[3*64*128];      // xg streams (P1,P2,P3)

// ---------------- helpers ----------------------------------------------------
__device__ inline float fdot2f(f16x2 a, f16x2 b, float c) {
#if __has_builtin(__builtin_amdgcn_fdot2)
  return __builtin_amdgcn_fdot2(a, b, c, false);
#else
  return c + (float)a[0]*(float)b[0] + (float)a[1]*(float)b[1];
#endif
}
__device__ inline float sigm_fast(float x) { return 1.0f / (1.0f + __expf(-x)); }
__device__ inline float tanh_fast(float x) { float e = __expf(2.0f*x); return 1.0f - 2.0f/(e + 1.0f); }
__device__ inline float lrelu(float x) { return x < 0.0f ? 0.2f*x : x; }
__device__ __forceinline__ void dot8x(f16x8 w, f16x8 h, float& a) {
  a = fdot2f(__builtin_shufflevector(w, w, 0, 1), __builtin_shufflevector(h, h, 0, 1), a);
  a = fdot2f(__builtin_shufflevector(w, w, 2, 3), __builtin_shufflevector(h, h, 2, 3), a);
  a = fdot2f(__builtin_shufflevector(w, w, 4, 5), __builtin_shufflevector(h, h, 4, 5), a);
  a = fdot2f(__builtin_shufflevector(w, w, 6, 7), __builtin_shufflevector(h, h, 6, 7), a);
}
// RELAXED spin + one ACQUIRE, single poller (tau==0), broadcast via barrier.
// R9-proven (4866us): removes per-thread LLC polls + L1 invalidates.
__device__ __forceinline__ void wait_ge(const unsigned* p, unsigned want) {
  while (__hip_atomic_load(p, __ATOMIC_RELAXED, __HIP_MEMORY_SCOPE_AGENT) < want) {}
  unsigned v;
  do { v = __hip_atomic_load(p, __ATOMIC_ACQUIRE, __HIP_MEMORY_SCOPE_AGENT); } while (v < want);
}

// ---------------- weight prep (UNCHANGED blob layout) -------------------------
__global__ void __launch_bounds__(256) k_prep_whh(const float* cw, const float* f0w, const float* fw) {
  int bid = blockIdx.x;               // 5120 = L*1024 + g
  int L = bid >> 10, g = bid & 1023, k = threadIdx.x;
  const float* src = (L == 0) ? cw : (L == 1) ? f0w : (fw + (size_t)(L-2)*262144u);
  int q = g >> 8, u = g & 255, r = u*4 + q;
  int ko = k >> 3, kl = k & 7;
  g_whhT2[(size_t)L*262144u + (size_t)(ko*1024 + r)*8u + kl] = (f16)src[(size_t)g*256 + k];
}
__global__ void __launch_bounds__(256) k_prep_wih(const float* fwih, const float* fbih, const float* fbhh) {
  int bid = blockIdx.x;               // 3072 = L*1024 + g
  int L = bid >> 10, g = bid & 1023, k = threadIdx.x;
  int q = g >> 8, u = g & 255, r = u*4 + q;
  int ko = k >> 3, kl = k & 7;
  g_wihO[(size_t)L*262144u + (size_t)(ko*1024 + r)*8u + kl] = (f16)fwih[(size_t)L*262144u + (size_t)g*256u + k];
  if (k == 0) g_biasP[L*1024 + r] = fbih[L*1024 + g] + fbhh[L*1024 + g];
}
__global__ void __launch_bounds__(256) k_prep_c1(const float* w) {
  int idx = blockIdx.x*256 + threadIdx.x;        // 655360
  int oc = idx / 2560, rem = idx % 2560, r = rem / 512, ic = rem % 512;
  g_B1[idx] = (f16)w[(size_t)oc*2560 + (size_t)ic*5 + r];
}
__global__ void __launch_bounds__(256) k_prep_c2(const float* w) {
  int idx = blockIdx.x*256 + threadIdx.x;        // 98304
  int oc = idx / 768, rem = idx % 768, r = rem / 256, ic = rem % 256;
  g_B2[idx] = (f16)w[(size_t)oc*768 + (size_t)ic*3 + r];
}
__global__ void __launch_bounds__(256) k_zero() {
  int idx = blockIdx.x*256 + threadIdx.x;        // 212992 = 832*256
  if (idx < 131072) {   // Xpad pad rows 0,1,1026,1027
    int b = idx >> 11, rem = idx & 2047, rr = rem >> 9, c = rem & 511;
    int row = (rr < 2) ? rr : 1024 + rr;
    g_Xpad[(size_t)b*526336u + (size_t)row*512u + c] = (f16)0.0f;
  } else if (idx < 163840) {   // c2in pad rows 0, 1025
    int i2 = idx - 131072;
    int b = i2 >> 9, rem = i2 & 511, rr = rem >> 8, c = rem & 255;
    int row = rr ? 1025 : 0;
    g_c2in[(size_t)b*262656u + (size_t)row*256u + c] = (f16)0.0f;
  } else {              // flags: MUST reset each launch (replay/graph safe)
    int i3 = idx - 163840;
    if (i3 < 24576) g_hflag[i3] = 0u;
    else            g_pflag[i3 - 24576] = 0u;
  }
}

// ---------------- small front-end ops ----------------------------------------
__global__ void __launch_bounds__(256) k_setup1(const float* z, const int* labels, const float* emb,
                                                const float* npw, const float* npb,
                                                const float* lg, const float* lb) {
  __shared__ float x[384];
  __shared__ float s1[256], s2[256];
  int b = blockIdx.x, tid = threadIdx.x;
  int lab = labels[b];
  for (int i = tid; i < 384; i += 256)
    x[i] = (i < 128) ? z[b*128 + i] : emb[lab*256 + (i - 128)];
  __syncthreads();
  float acc = npb[tid];
  for (int k = 0; k < 384; ++k) acc += npw[tid*384 + k]*x[k];
  s1[tid] = acc; s2[tid] = acc*acc; __syncthreads();
  for (int s = 128; s > 0; s >>= 1) { if (tid < s) { s1[tid]+=s1[tid+s]; s2[tid]+=s2[tid+s]; } __syncthreads(); }
  float m = s1[0]*(1.0f/256.0f), var = s2[0]*(1.0f/256.0f) - m*m;
  float hv = (acc - m)*(1.0f/sqrtf(var + 1e-5f))*lg[tid] + lb[tid];
  hv = lrelu(hv);
  g_h[b*256 + tid] = hv;
  g_cat512[b*512 + tid] = hv;
  g_cat512[b*512 + 256 + tid] = x[128 + tid];
}
__global__ void __launch_bounds__(1024) k_xg0(const float* cwih, const float* cbih, const float* cbhh,
                                              const float* fwih, const float* fbih, const float* fbhh) {
  int bid = blockIdx.x;               // 128 = layer*64+b
  int layer = bid >> 6, b = bid & 63;
  int gp = threadIdx.x, j = gp >> 2, q = gp & 3, g = q*256 + j;
  __shared__ float cat[512];
  if (gp < 512) cat[gp] = g_cat512[b*512 + gp];
  __syncthreads();
  const float* w = layer ? fwih : cwih;
  float acc = layer ? (fbih[g] + fbhh[g]) : (cbih[g] + cbhh[g]);
  for (int k = 0; k < 512; ++k) acc += w[(size_t)g*512 + k]*cat[k];
  g_xg0[(layer*64 + b)*1024 + gp] = acc;
}
__global__ void __launch_bounds__(256) k_osc(const float* w1, const float* b1v, const float* lg,
                                             const float* lb, const float* w2, const float* b2v) {
  __shared__ float hb[256], av[256], s1[256], s2[256];
  int b = blockIdx.x, tid = threadIdx.x;
  hb[tid] = g_h[b*256 + tid];
  __syncthreads();
  float acc = b1v[tid];
  for (int k = 0; k < 256; ++k) acc += w1[tid*256 + k]*hb[k];
  s1[tid] = acc; s2[tid] = acc*acc; __syncthreads();
  for (int s = 128; s > 0; s >>= 1) { if (tid < s) { s1[tid]+=s1[tid+s]; s2[tid]+=s2[tid+s]; } __syncthreads(); }
  float m = s1[0]*(1.0f/256.0f), var = s2[0]*(1.0f/256.0f) - m*m;
  av[tid] = lrelu((acc - m)*(1.0f/sqrtf(var + 1e-5f))*lg[tid] + lb[tid]);
  __syncthreads();
  for (int tt = tid; tt < 1024; tt += 256) {
    float o = b2v[tt];
    for (int i = 0; i < 256; ++i) o += w2[(size_t)tt*256 + i]*av[i];
    g_osc[b*1024 + tt] = tanhf(o);
  }
}
__global__ void __launch_bounds__(256) k_sinmean(const float* sw, const float* sb) {
  int tt = blockIdx.x*256 + threadIdx.x;   // grid 4
  const float F[6] = {0.19f, 0.21f, 0.23f, 0.25f, 0.27f, 0.29f};
  float tl = tt*(1.0f/1023.0f);
  float sc[12];
  for (int j = 0; j < 6; ++j) {
    float p = (6.2831853071795864f * tl) * F[j] * 1024.0f;
    sc[j] = sinf(p); sc[6 + j] = cosf(p);
  }
  float a = 0.0f;
  for (int i = 0; i < 128; ++i) {
    float s = sb[i];
    for (int j = 0; j < 12; ++j) s += sw[i*12 + j]*sc[j];
    a += s;
  }
  g_smean[tt] = a*(1.0f/128.0f);
}

// ---------------- the whole LSTM stack as ONE flag-chained dispatch ----------
// R9-proven schedule (4866us): 512 blocks x 512 thr, 1 block/CU, two implicit
// dispatch waves (depth<=4 live chain). Roles by bid>>6 (b = bid&63):
//  0 coarse | 1 f0 | 2 P1 | 3 f1 || 4 P2 | 5 f2 | 6 P3 | 7 f3
// SPLIT-K dot (R10-proven best, 4823us): thread tau (kh=tau>>8, j=tau&255)
// owns 4 rows {j,j+256,j+512,j+768} x k-half [128kh,128kh+128). Same
// per-thread MACs and 48-f16x8 register footprint (no spill), h-broadcast
// reads halved; partials meet in gbuf[2][1024]. Two-barrier exchange kept:
// R11/R13 proved the shfl alternatives regress (redundant VALU / divergence).
__global__ void __launch_bounds__(512, 2) k_chain() {
  int bid = blockIdx.x;             // 512
  int role = bid >> 6, b = bid & 63;
  int tau = threadIdx.x;            // 0..511
  int kh = tau >> 8, j = tau & 255;
  bool isP = (role == 2) || (role == 4) || (role == 6);
  int lp = (role - 2) >> 1;                                      // P idx 0..2
  int Lg = (role==0)?0:(role==1)?1:(role==3)?2:(role==5)?3:4;    // gate whh layer

  __shared__ __align__(16) f16 wlds[65536];    // planes {0,1,2,3,16,17,18,19} (128 KB)
  __shared__ __align__(16) f16 hbuf[2][256];
  __shared__ __align__(16) float gbuf[2048];   // [kh][row] partials

  const f16* Wc = isP ? (g_wihO + (size_t)lp*262144u) : (g_whhT2 + (size_t)Lg*262144u);
  // LDS staging: 8 octet-planes; plane p -> blob octet ko = p<4 ? p : p+12
#pragma unroll
  for (int i = 0; i < 16; ++i) {
    int o = i*512 + tau;                       // 0..8191 = p*1024 + row
    int p = o >> 10, rr = o & 1023;
    int ko = (p < 4) ? p : (p + 12);
    *(f16x8*)(wlds + (size_t)o*8u) = *(const f16x8*)(Wc + (size_t)(ko*1024 + rr)*8u);
  }
  // regs: octets m=0..11 -> ko = 16kh+4+m; rows i=0..3 (j+256i). 48 f16x8.
  f16x8 wR[48];
#pragma unroll
  for (int m = 0; m < 12; ++m)
#pragma unroll
    for (int i = 0; i < 4; ++i)
      wR[m*4 + i] = *(const f16x8*)(Wc + (size_t)((16*kh + 4 + m)*1024 + j + 256*i)*8u);

  if (isP) {
    // -------- projection: xg_l(t) = wih_l . h_stream(t) + bias ----------------
    const f16* hs = ((lp==0) ? g_fseqA : (lp==1) ? g_fseqB : g_fseqC) + (size_t)b*262144u;
    const unsigned* hf = g_hflag + (lp*64 + b)*128;
    float* xo = g_xg32 + (size_t)(lp*64 + b)*1048576u;
    unsigned* pf = g_pflag + (lp*64 + b)*128;
    f32x4 bias4 = {0.f,0.f,0.f,0.f};
    if (tau < 256) bias4 = *(const f32x4*)(g_biasP + lp*1024 + 4*tau);
    __syncthreads();
#pragma unroll 1
    for (int t = 0; t < 1024; ++t) {
      if ((t & 7) == 0) {            // single poller + barrier broadcast
        if (tau == 0) wait_ge(hf + (t >> 3), (unsigned)(t >> 3) + 1u);
        __syncthreads();
      }
      if (tau < 32) *(f16x8*)(&hbuf[t & 1][tau*8]) = *(const f16x8*)(hs + (size_t)t*256u + tau*8);
      __syncthreads();
      const f16* hb = &hbuf[t & 1][kh*128];
      float p0 = 0.f, p1 = 0.f, p2 = 0.f, p3 = 0.f;
#pragma unroll
      for (int c = 0; c < 4; ++c) {            // LDS octets (plane 4kh+c)
        f16x8 hv = *(const f16x8*)(hb + c*8);
        int pl = 4*kh + c;
        dot8x(*(const f16x8*)(wlds + (size_t)(pl*1024 + j)*8u),       hv, p0);
        dot8x(*(const f16x8*)(wlds + (size_t)(pl*1024 + j + 256)*8u), hv, p1);
        dot8x(*(const f16x8*)(wlds + (size_t)(pl*1024 + j + 512)*8u), hv, p2);
        dot8x(*(const f16x8*)(wlds + (size_t)(pl*1024 + j + 768)*8u), hv, p3);
      }
#pragma unroll
      for (int m = 0; m < 12; ++m) {           // reg octets (k = 128kh+32+8m)
        f16x8 hv = *(const f16x8*)(hb + 32 + m*8);
        dot8x(wR[m*4 + 0], hv, p0);
        dot8x(wR[m*4 + 1], hv, p1);
        dot8x(wR[m*4 + 2], hv, p2);
        dot8x(wR[m*4 + 3], hv, p3);
      }
      gbuf[kh*1024 + j]       = p0;
      gbuf[kh*1024 + j + 256] = p1;
      gbuf[kh*1024 + j + 512] = p2;
      gbuf[kh*1024 + j + 768] = p3;
      __syncthreads();
      if (tau < 256) {
        f32x4 gA = *(const f32x4*)(&gbuf[4*tau]);
        f32x4 gB = *(const f32x4*)(&gbuf[1024 + 4*tau]);
        f32x4 v;
        v[0] = gA[0] + gB[0] + bias4[0]; v[1] = gA[1] + gB[1] + bias4[1];
        v[2] = gA[2] + gB[2] + bias4[2]; v[3] = gA[3] + gB[3] + bias4[3];
        *(f32x4*)(xo + (size_t)t*1024u + 4*tau) = v;
      }
      if ((t & 7) == 7) {
        __syncthreads();             // drains xg stores of the group before flag
        if (tau == 0) __hip_atomic_store(pf + (t >> 3), (unsigned)(t >> 3) + 1u,
                                         __ATOMIC_RELEASE, __HIP_MEMORY_SCOPE_AGENT);
      }
    }
  } else {
    // -------- gate: LSTM recurrence (split-k body) ----------------------------
    bool dyn = (role >= 3);
    int lq = (role - 3) >> 1;       // xg stream idx (valid when dyn)
    float c0 = 0.0f, sum0 = 0.0f;
    f32x4 xg4 = {0.f, 0.f, 0.f, 0.f};
    const f32x4* xp = nullptr;
    const unsigned* xf = nullptr;
    f16* outp = nullptr; int ostride = 0;
    unsigned* hfo = nullptr;
    if (tau < 256) {
      hbuf[0][tau] = (f16)0.0f;
      if (!dyn) xg4 = *(const f32x4*)(g_xg0 + (size_t)(Lg*64 + b)*1024u + 4*tau);
      else      xp  = (const f32x4*)(g_xg32 + (size_t)(lq*64 + b)*1048576u) + tau;
      if (role == 0)      { outp = g_Xpad  + (size_t)b*526336u + 1024 + tau;       ostride = 512; }
      else if (role == 1) { outp = g_fseqA + (size_t)b*262144u + tau;              ostride = 256; }
      else if (role == 3) { outp = g_fseqB + (size_t)b*262144u + tau;              ostride = 256; }
      else if (role == 5) { outp = g_fseqC + (size_t)b*262144u + tau;              ostride = 256; }
      else                { outp = g_Xpad  + (size_t)b*526336u + 1024 + 256 + tau; ostride = 512; }
    }
    if (dyn) xf = g_pflag + (lq*64 + b)*128;
    int hop = (role == 1) ? 0 : (role == 3) ? 1 : (role == 5) ? 2 : -1;
    if (hop >= 0) hfo = g_hflag + (hop*64 + b)*128;
    __syncthreads();
    int cur = 0;
#pragma unroll 1
    for (int step = 0; step < 1024; ++step) {
      if (dyn && (step & 7) == 0) {  // single poller + barrier broadcast
        if (tau == 0) wait_ge(xf + (step >> 3), (unsigned)(step >> 3) + 1u);
        __syncthreads();
      }
      f32x4 xv = xg4;
      if (dyn && tau < 256)
        xv = xp[(size_t)step*256u]; // issued before dots -> latency hidden
      const f16* hb = &hbuf[cur][kh*128];
      float p0 = 0.f, p1 = 0.f, p2 = 0.f, p3 = 0.f;
#pragma unroll
      for (int c = 0; c < 4; ++c) {
        f16x8 hv = *(const f16x8*)(hb + c*8);
        int pl = 4*kh + c;
        dot8x(*(const f16x8*)(wlds + (size_t)(pl*1024 + j)*8u),       hv, p0);
        dot8x(*(const f16x8*)(wlds + (size_t)(pl*1024 + j + 256)*8u), hv, p1);
        dot8x(*(const f16x8*)(wlds + (size_t)(pl*1024 + j + 512)*8u), hv, p2);
        dot8x(*(const f16x8*)(wlds + (size_t)(pl*1024 + j + 768)*8u), hv, p3);
      }
#pragma unroll
      for (int m = 0; m < 12; ++m) {
        f16x8 hv = *(const f16x8*)(hb + 32 + m*8);
        dot8x(wR[m*4 + 0], hv, p0);
        dot8x(wR[m*4 + 1], hv, p1);
        dot8x(wR[m*4 + 2], hv, p2);
        dot8x(wR[m*4 + 3], hv, p3);
      }
      gbuf[kh*1024 + j]       = p0;
      gbuf[kh*1024 + j + 256] = p1;
      gbuf[kh*1024 + j + 512] = p2;
      gbuf[kh*1024 + j + 768] = p3;
      __syncthreads();
      if (tau < 256) {
        f32x4 gA = *(const f32x4*)(&gbuf[4*tau]);
        f32x4 gB = *(const f32x4*)(&gbuf[1024 + 4*tau]);
        float ii = sigm_fast(gA[0] + gB[0] + xv[0]);
        float ff = sigm_fast(gA[1] + gB[1] + xv[1]);
        float gg = tanh_fast(gA[2] + gB[2] + xv[2]);
        float oo = sigm_fast(gA[3] + gB[3] + xv[3]);
        c0 = ff*c0 + ii*gg;
        float h0 = oo*tanh_fast(c0); sum0 += h0;
        hbuf[cur ^ 1][tau] = (f16)h0;
        outp[(size_t)step*ostride] = (f16)h0;
      }
      __syncthreads();               // h stores drained (per-wave vmcnt at barrier)
      if (hfo && (step & 7) == 7 && tau == 0)
        __hip_atomic_store(hfo + (step >> 3), (unsigned)(step >> 3) + 1u,
                           __ATOMIC_RELEASE, __HIP_MEMORY_SCOPE_AGENT);
      cur ^= 1;
    }
    if (tau < 256) {
      if (role == 0) g_feats[b*512 + tau]       = sum0*(1.0f/1024.0f);
      if (role == 7) g_feats[b*512 + 256 + tau] = sum0*(1.0f/1024.0f);
    }
  }
}

// ---------------- fp16 MFMA GEMM (implicit conv1/conv2) ----------------------
__global__ void __launch_bounds__(256) k_gemm(int which,
                                              const float* cb, const float* bng, const float* bnb) {
  const f16* A; size_t a_bs; int a_rs, K; const f16* Bm;
  f16* outH; size_t o_bs; int o_rs;
  if (which == 2) {
    A = g_Xpad; a_bs = 526336u; a_rs = 512; K = 2560; Bm = g_B1;
    outH = g_c2in + 256; o_bs = 262656u; o_rs = 256;
  } else {
    A = g_c2in; a_bs = 262656u; a_rs = 256; K = 768; Bm = g_B2;
    outH = g_c3in; o_bs = 131072u; o_rs = 128;
  }
  int tid = threadIdx.x, wave = tid >> 6, lane = tid & 63;
  int m0 = blockIdx.x*128, n0 = blockIdx.y*64;
  __shared__ __align__(16) f16 Asm[128*72];
  __shared__ __align__(16) f16 Bsm[64*72];
  f32x4 acc[2][4];
#pragma unroll
  for (int i = 0; i < 2; ++i)
#pragma unroll
    for (int jj = 0; jj < 4; ++jj) { f32x4 zz = {0.f,0.f,0.f,0.f}; acc[i][jj] = zz; }
  int ar = tid & 127, ac = (tid >> 7)*32;
  int mrow = m0 + ar, abb = mrow >> 10, att = mrow & 1023;
  const f16* aptr = A + (size_t)abb*a_bs + (size_t)att*a_rs + ac;
  int br = tid & 63, bc = (tid >> 6)*16;
  const f16* bptr = Bm + (size_t)(n0 + br)*K + bc;
  int nkb = K >> 6;
  for (int kb = 0; kb < nkb; ++kb) {
    f16x8 av0 = *(const f16x8*)(aptr + 0);
    f16x8 av1 = *(const f16x8*)(aptr + 8);
    f16x8 av2 = *(const f16x8*)(aptr + 16);
    f16x8 av3 = *(const f16x8*)(aptr + 24);
    f16x8 bv0 = *(const f16x8*)(bptr + 0);
    f16x8 bv1 = *(const f16x8*)(bptr + 8);
    aptr += 64; bptr += 64;
    __syncthreads();
    *(f16x8*)(&Asm[ar*72 + ac + 0])  = av0;
    *(f16x8*)(&Asm[ar*72 + ac + 8])  = av1;
    *(f16x8*)(&Asm[ar*72 + ac + 16]) = av2;
    *(f16x8*)(&Asm[ar*72 + ac + 24]) = av3;
    *(f16x8*)(&Bsm[br*72 + bc + 0])  = bv0;
    *(f16x8*)(&Bsm[br*72 + bc + 8])  = bv1;
    __syncthreads();
#pragma unroll
    for (int ks = 0; ks < 2; ++ks) {
      int ko = ks*32 + (lane >> 4)*8;
      f16x8 a0 = *(const f16x8*)(&Asm[(wave*32 + (lane & 15))*72 + ko]);
      f16x8 a1 = *(const f16x8*)(&Asm[(wave*32 + 16 + (lane & 15))*72 + ko]);
#pragma unroll
      for (int nt = 0; nt < 4; ++nt) {
        f16x8 bf = *(const f16x8*)(&Bsm[(nt*16 + (lane & 15))*72 + ko]);
        acc[0][nt] = __builtin_amdgcn_mfma_f32_16x16x32_f16(a0, bf, acc[0][nt], 0, 0, 0);
        acc[1][nt] = __builtin_amdgcn_mfma_f32_16x16x32_f16(a1, bf, acc[1][nt], 0, 0, 0);
      }
    }
  }
  const float bnc = 0.99999500003749969f;  // 1/sqrt(1+1e-5)
#pragma unroll
  for (int mt = 0; mt < 2; ++mt)
#pragma unroll
    for (int nt = 0; nt < 4; ++nt)
#pragma unroll
      for (int r = 0; r < 4; ++r) {
        int m_loc = wave*32 + mt*16 + (lane >> 4)*4 + r;
        int n = n0 + nt*16 + (lane & 15);
        int mg = m0 + m_loc, ob = mg >> 10, ot = mg & 1023;
        float v = acc[mt][nt][r];
        v = (v + cb[n])*(bng[n]*bnc) + bnb[n];
        v = lrelu(v);
        outH[(size_t)ob*o_bs + (size_t)ot*o_rs + n] = (f16)v;
      }
}

// ---------------- cp head ----------------------------------------------------
__global__ void __launch_bounds__(128) k_cp(const float* w1, const float* b1v, const float* lg,
                                            const float* lb, const float* w2, const float* b2v) {
  __shared__ float ft[512], av[128], s1[128], s2[128];
  int b = blockIdx.x, tid = threadIdx.x;
  for (int i = tid; i < 512; i += 128) ft[i] = g_feats[b*512 + i];
  __syncthreads();
  float acc = b1v[tid];
  for (int k = 0; k < 512; ++k) acc += w1[tid*512 + k]*ft[k];
  s1[tid] = acc; s2[tid] = acc*acc; __syncthreads();
  for (int s = 64; s > 0; s >>= 1) { if (tid < s) { s1[tid]+=s1[tid+s]; s2[tid]+=s2[tid+s]; } __syncthreads(); }
  float m = s1[0]*(1.0f/128.0f), var = s2[0]*(1.0f/128.0f) - m*m;
  av[tid] = lrelu((acc - m)*(1.0f/sqrtf(var + 1e-5f))*lg[tid] + lb[tid]);
  __syncthreads();
  if (tid < 4) {
    float s = b2v[tid];
    for (int i = 0; i < 128; ++i) s += w2[tid*128 + i]*av[i];
    g_cpar[b*4 + tid] = 1.0f/(1.0f + expf(-s));
  }
}

// ---------------- conv3 + enhanced -------------------------------------------
__global__ void __launch_bounds__(256) k_enh(const float* w3, const float* b3) {
  int idx = blockIdx.x*256 + threadIdx.x;
  int b = idx >> 10, t = idx & 1023;
  const f16* xc = g_c3in + (size_t)idx*128u;
  bool hm = (t > 0), hp = (t < 1023);
  float pre = b3[0];
  for (int c = 0; c < 128; ++c) {
    float xm = hm ? (float)xc[c - 128] : 0.0f;
    float x0 = (float)xc[c];
    float xp = hp ? (float)xc[c + 128] : 0.0f;
    pre += xm*w3[c*3] + x0*w3[c*3 + 1] + xp*w3[c*3 + 2];
  }
  float base = tanhf(pre);
  float cp0 = g_cpar[b*4 + 0], cp1 = g_cpar[b*4 + 1], cp2 = g_cpar[b*4 + 2], cp3 = g_cpar[b*4 + 3];
  float freq  = 0.19f + 0.1f*cp0;
  float amp   = 1.0f + 2.0f*cp1;
  float phase = 6.2831853071795864f*cp2;
  float basel = -0.5f + cp3;
  float tl = t*(1.0f/1023.0f);
  float arg = ((6.2831853071795864f*freq)*1024.0f)*tl + phase;
  float card = amp*sinf(arg) + basel;
  g_enh[idx] = 0.1f*base + 0.1f*g_osc[idx] + 0.7f*card + 0.1f*g_smean[t];
}

__global__ void __launch_bounds__(256) k_out(const int* labels, const float* sw,
                                             const float* aw, const float* ab, float* out) {
  int idx = blockIdx.x*256 + threadIdx.x;
  int b = idx >> 10, t = idx & 1023;
  int lab = labels[b];
  float e = g_enh[idx], r;
  if (lab == 1) r = e;
  else if (lab == 2) r = sw[0]*e;
  else if (lab == 3) {
    float em = (t > 0)    ? g_enh[idx - 1] : 0.0f;
    float ep = (t < 1023) ? g_enh[idx + 1] : 0.0f;
    r = aw[0]*em + aw[1]*e + aw[2]*ep + ab[0];
  } else r = 0.0f;
  out[idx] = r;
}

// ---------------- launch ------------------------------------------------------
extern "C" void kernel_launch(void* const* d_in, const int* in_sizes, int n_in,
                              void* d_out, int out_size, void* d_ws, size_t ws_size,
                              hipStream_t stream) {
  const float* z       = (const float*)d_in[0];
  const int*   labels  = (const int*)  d_in[1];
  const float* emb     = (const float*)d_in[2];
  const float* np_w    = (const float*)d_in[3];
  const float* np_b    = (const float*)d_in[4];
  const float* np_ln_g = (const float*)d_in[5];
  const float* np_ln_b = (const float*)d_in[6];
  const float* c_wih   = (const float*)d_in[7];
  const float* c_whh   = (const float*)d_in[8];
  const float* c_bih   = (const float*)d_in[9];
  const float* c_bhh   = (const float*)d_in[10];
  const float* f0_wih  = (const float*)d_in[11];
  const float* f0_whh  = (const float*)d_in[12];
  const float* f0_bih  = (const float*)d_in[13];
  const float* f0_bhh  = (const float*)d_in[14];
  const float* f_wih   = (const float*)d_in[15];
  const float* f_whh   = (const float*)d_in[16];
  const float* f_bih   = (const float*)d_in[17];
  const float* f_bhh   = (const float*)d_in[18];
  const float* osc_w1  = (const float*)d_in[19];
  const float* osc_b1  = (const float*)d_in[20];
  const float* osc_ln_g= (const float*)d_in[21];
  const float* osc_ln_b= (const float*)d_in[22];
  const float* osc_w2  = (const float*)d_in[23];
  const float* osc_b2  = (const float*)d_in[24];
  const float* cp_w1   = (const float*)d_in[25];
  const float* cp_b1   = (const float*)d_in[26];
  const float* cp_ln_g = (const float*)d_in[27];
  const float* cp_ln_b = (const float*)d_in[28];
  const float* cp_w2   = (const float*)d_in[29];
  const float* cp_b2   = (const float*)d_in[30];
  const float* sin_w   = (const float*)d_in[31];
  const float* sin_b   = (const float*)d_in[32];
  const float* conv1_w = (const float*)d_in[33];
  const float* conv1_b = (const float*)d_in[34];
  const float* bn1_g   = (const float*)d_in[35];
  const float* bn1_b   = (const float*)d_in[36];
  const float* conv2_w = (const float*)d_in[37];
  const float* conv2_b = (const float*)d_in[38];
  const float* bn2_g   = (const float*)d_in[39];
  const float* bn2_b   = (const float*)d_in[40];
  const float* conv3_w = (const float*)d_in[41];
  const float* conv3_b = (const float*)d_in[42];
  const float* stress_w= (const float*)d_in[43];
  const float* amuse_w = (const float*)d_in[44];
  const float* amuse_b = (const float*)d_in[45];
  float* out = (float*)d_out;

  k_prep_whh<<<5120, 256, 0, stream>>>(c_whh, f0_whh, f_whh);
  k_prep_wih<<<3072, 256, 0, stream>>>(f_wih, f_bih, f_bhh);
  k_prep_c1 <<<2560, 256, 0, stream>>>(conv1_w);
  k_prep_c2 <<< 384, 256, 0, stream>>>(conv2_w);
  k_zero    <<< 832, 256, 0, stream>>>();
  k_setup1  <<<  64, 256, 0, stream>>>(z, labels, emb, np_w, np_b, np_ln_g, np_ln_b);
  k_xg0     <<< 128,1024, 0, stream>>>(c_wih, c_bih, c_bhh, f0_wih, f0_bih, f0_bhh);
  k_osc     <<<  64, 256, 0, stream>>>(osc_w1, osc_b1, osc_ln_g, osc_ln_b, osc_w2, osc_b2);
  k_sinmean <<<   4, 256, 0, stream>>>(sin_w, sin_b);

  k_chain   <<< 512, 512, 0, stream>>>();        // all 5 LSTM layers + 3 projections

  k_cp      <<<  64, 128, 0, stream>>>(cp_w1, cp_b1, cp_ln_g, cp_ln_b, cp_w2, cp_b2);
  k_gemm    <<<dim3(512, 4), 256, 0, stream>>>(2, conv1_b, bn1_g, bn1_b);   // conv1
  k_gemm    <<<dim3(512, 2), 256, 0, stream>>>(3, conv2_b, bn2_g, bn2_b);   // conv2
  k_enh     <<< 256, 256, 0, stream>>>(conv3_w, conv3_b);
  k_out     <<< 256, 256, 0, stream>>>(labels, stress_w, amuse_w, amuse_b, out);
}